// Round 4
// baseline (317.264 us; speedup 1.0000x reference)
//
#include <hip/hip_runtime.h>

// 2D DWT (db2, symmetric pad, pywt-compatible) v4: v3 + row-loop unroll-by-2.
// x: (16,3,1024,1024) f32 -> cA, cH: (16,3,513,513) f32, concatenated in d_out.
//
// v3 (310.7us total) proved: 256thr / TI=8 / 3120 blocks / wave-private LDS
// bounce / dense dword stores. v4 keeps all of that and restructures the row
// loop to process 2 output rows per iteration:
//  - state: 2 carried xp rows (a) + 4 prefetched xp rows (p)
//  - both verticals computed FIRST (p dead) -> rotate -> prefetch 8 loads
//    issued immediately; in flight across both rows' horizontal + LDS + 8
//    stores (2x the latency-cover window of v3, half the vmcnt waits/row).
// VGPR ~72 -> launch_bounds(256,6): 6-7 waves/SIMD, 24-28 waves/CU.

#define N 1024
#define NOUT 513
#define TI 8
#define STRIPS ((NOUT + TI - 1) / TI)   // 65
#define NIMG 48

__device__ __forceinline__ int refl(int p) {
    int r = p - 2;
    r = (r < 0) ? (-1 - r) : r;
    r = (r > N - 1) ? (2 * N - 1 - r) : r;
    return r;
}

__device__ __forceinline__ float4 comb4(float w0, const float4 a, float w1, const float4 b,
                                        float w2, const float4 c, float w3, const float4 d) {
    float4 r;
    r.x = fmaf(w0, a.x, fmaf(w1, b.x, fmaf(w2, c.x, w3 * d.x)));
    r.y = fmaf(w0, a.y, fmaf(w1, b.y, fmaf(w2, c.y, w3 * d.y)));
    r.z = fmaf(w0, a.z, fmaf(w1, b.z, fmaf(w2, c.z, w3 * d.z)));
    r.w = fmaf(w0, a.w, fmaf(w1, b.w, fmaf(w2, c.w, w3 * d.w)));
    return r;
}

__device__ __forceinline__ float2 comb2(float w0, const float2 a, float w1, const float2 b,
                                        float w2, const float2 c, float w3, const float2 d) {
    float2 r;
    r.x = fmaf(w0, a.x, fmaf(w1, b.x, fmaf(w2, c.x, w3 * d.x)));
    r.y = fmaf(w0, a.y, fmaf(w1, b.y, fmaf(w2, c.y, w3 * d.y)));
    return r;
}

__global__ __launch_bounds__(256, 6) void dwt2_v4(const float* __restrict__ x,
                                                  float* __restrict__ out) {
    // reversed filter taps (true convolution)
    const float l0 =  0.48296291314469025f;
    const float l1 =  0.836516303737469f;
    const float l2 =  0.22414386804185735f;
    const float l3 = -0.12940952255092145f;
    const float h0 = -0.12940952255092145f;
    const float h1 = -0.22414386804185735f;
    const float h2 =  0.836516303737469f;
    const float h3 = -0.48296291314469025f;

    __shared__ float sA[4][2][128];   // [wave][row][col] 4 KB
    __shared__ float sH[4][2][128];   // 4 KB

    const int strip = blockIdx.x;
    const int img   = blockIdx.y;
    const int i0 = strip * TI;
    const int u    = threadIdx.x;        // 0..255
    const int wave = u >> 6;
    const int lane = u & 63;
    const int c4 = 4 * u;                // owned input cols c4..c4+3
    const int ce = (u == 0) ? 0 : (c4 - 2);

    const float* xim = x + (size_t)img * N * N;
    const size_t plane = (size_t)NOUT * NOUT;
    float* cA = out + (size_t)img * plane;
    float* cH = out + ((size_t)NIMG + img) * plane;

    const int nrows = (NOUT - i0 < TI) ? (NOUT - i0) : TI;   // 8, or 1 (strip 64)

    // prologue: a = xp[2i0, 2i0+1]; p0..p3 = xp[2i0+2 .. 2i0+5]
    const float* q;
    q = xim + (size_t)refl(2 * i0)     * N;
    float4 a0m = *reinterpret_cast<const float4*>(q + c4);
    float2 a0e = *reinterpret_cast<const float2*>(q + ce);
    q = xim + (size_t)refl(2 * i0 + 1) * N;
    float4 a1m = *reinterpret_cast<const float4*>(q + c4);
    float2 a1e = *reinterpret_cast<const float2*>(q + ce);
    q = xim + (size_t)refl(2 * i0 + 2) * N;
    float4 p0m = *reinterpret_cast<const float4*>(q + c4);
    float2 p0e = *reinterpret_cast<const float2*>(q + ce);
    q = xim + (size_t)refl(2 * i0 + 3) * N;
    float4 p1m = *reinterpret_cast<const float4*>(q + c4);
    float2 p1e = *reinterpret_cast<const float2*>(q + ce);
    q = xim + (size_t)refl(2 * i0 + 4) * N;
    float4 p2m = *reinterpret_cast<const float4*>(q + c4);
    float2 p2e = *reinterpret_cast<const float2*>(q + ce);
    q = xim + (size_t)refl(2 * i0 + 5) * N;
    float4 p3m = *reinterpret_cast<const float4*>(q + c4);
    float2 p3e = *reinterpret_cast<const float2*>(q + ce);

    int ii = 0;
    for (; ii + 1 < nrows; ii += 2) {
        const int i = i0 + ii;

        // ---- verticals for rows i (v*) and i+1 (w*); p dead afterwards ----
        float4 vloM = comb4(l0, a0m, l1, a1m, l2, p0m, l3, p1m);
        float2 vloE = comb2(l0, a0e, l1, a1e, l2, p0e, l3, p1e);
        float4 vhiM = comb4(h0, a0m, h1, a1m, h2, p0m, h3, p1m);
        float2 vhiE = comb2(h0, a0e, h1, a1e, h2, p0e, h3, p1e);
        float4 wloM = comb4(l0, p0m, l1, p1m, l2, p2m, l3, p3m);
        float2 wloE = comb2(l0, p0e, l1, p1e, l2, p2e, l3, p3e);
        float4 whiM = comb4(h0, p0m, h1, p1m, h2, p2m, h3, p3m);
        float2 whiE = comb2(h0, p0e, h1, p1e, h2, p2e, h3, p3e);

        if (u == 0) {   // left image edge: j=0 uses xp cols (1,0,0,1)
            vloE = make_float2(vloM.y, vloM.x);
            vhiE = make_float2(vhiM.y, vhiM.x);
            wloE = make_float2(wloM.y, wloM.x);
            whiE = make_float2(whiM.y, whiM.x);
        }

        // ---- rotate a <- p2,p3; prefetch next 4 rows into p (in flight
        //      across horizontals + LDS + stores below) ----
        a0m = p2m; a0e = p2e;
        a1m = p3m; a1e = p3e;
        if (ii + 3 < nrows) {
            q = xim + (size_t)refl(2 * i + 6) * N;
            p0m = *reinterpret_cast<const float4*>(q + c4);
            p0e = *reinterpret_cast<const float2*>(q + ce);
            q = xim + (size_t)refl(2 * i + 7) * N;
            p1m = *reinterpret_cast<const float4*>(q + c4);
            p1e = *reinterpret_cast<const float2*>(q + ce);
            q = xim + (size_t)refl(2 * i + 8) * N;
            p2m = *reinterpret_cast<const float4*>(q + c4);
            p2e = *reinterpret_cast<const float2*>(q + ce);
            q = xim + (size_t)refl(2 * i + 9) * N;
            p3m = *reinterpret_cast<const float4*>(q + c4);
            p3e = *reinterpret_cast<const float2*>(q + ce);
        }

        // ---- horizontals: row i -> outputs j=2u,2u+1 ----
        float oA0 = fmaf(l0, vloE.x, fmaf(l1, vloE.y, fmaf(l2, vloM.x, l3 * vloM.y)));
        float oA1 = fmaf(l0, vloM.x, fmaf(l1, vloM.y, fmaf(l2, vloM.z, l3 * vloM.w)));
        float oH0 = fmaf(l0, vhiE.x, fmaf(l1, vhiE.y, fmaf(l2, vhiM.x, l3 * vhiM.y)));
        float oH1 = fmaf(l0, vhiM.x, fmaf(l1, vhiM.y, fmaf(l2, vhiM.z, l3 * vhiM.w)));
        float eA0 = fmaf(l0, vloM.z, fmaf(l1, vloM.w, fmaf(l2, vloM.w, l3 * vloM.z)));
        float eH0 = fmaf(l0, vhiM.z, fmaf(l1, vhiM.w, fmaf(l2, vhiM.w, l3 * vhiM.z)));
        // ---- horizontals: row i+1 ----
        float oA2 = fmaf(l0, wloE.x, fmaf(l1, wloE.y, fmaf(l2, wloM.x, l3 * wloM.y)));
        float oA3 = fmaf(l0, wloM.x, fmaf(l1, wloM.y, fmaf(l2, wloM.z, l3 * wloM.w)));
        float oH2 = fmaf(l0, whiE.x, fmaf(l1, whiE.y, fmaf(l2, whiM.x, l3 * whiM.y)));
        float oH3 = fmaf(l0, whiM.x, fmaf(l1, whiM.y, fmaf(l2, whiM.z, l3 * whiM.w)));
        float eA1 = fmaf(l0, wloM.z, fmaf(l1, wloM.w, fmaf(l2, wloM.w, l3 * wloM.z)));
        float eH1 = fmaf(l0, whiM.z, fmaf(l1, whiM.w, fmaf(l2, whiM.w, l3 * whiM.z)));

        // ---- wave-private LDS bounce (b64 writes) -> lane-dense stores ----
        *reinterpret_cast<float2*>(&sA[wave][0][2 * lane]) = make_float2(oA0, oA1);
        *reinterpret_cast<float2*>(&sA[wave][1][2 * lane]) = make_float2(oA2, oA3);
        *reinterpret_cast<float2*>(&sH[wave][0][2 * lane]) = make_float2(oH0, oH1);
        *reinterpret_cast<float2*>(&sH[wave][1][2 * lane]) = make_float2(oH2, oH3);
        __builtin_amdgcn_wave_barrier();   // compile-time order pin (free)
        float rA0 = sA[wave][0][lane];
        float rA1 = sA[wave][0][64 + lane];
        float rA2 = sA[wave][1][lane];
        float rA3 = sA[wave][1][64 + lane];
        float rH0 = sH[wave][0][lane];
        float rH1 = sH[wave][0][64 + lane];
        float rH2 = sH[wave][1][lane];
        float rH3 = sH[wave][1][64 + lane];

        const int j0 = (wave << 7) + lane;
        float* pa0 = cA + (size_t)i * NOUT;
        float* pa1 = pa0 + NOUT;
        float* ph0 = cH + (size_t)i * NOUT;
        float* ph1 = ph0 + NOUT;
        pa0[j0]      = rA0;
        pa0[j0 + 64] = rA1;
        pa1[j0]      = rA2;
        pa1[j0 + 64] = rA3;
        ph0[j0]      = rH0;
        ph0[j0 + 64] = rH1;
        ph1[j0]      = rH2;
        ph1[j0 + 64] = rH3;

        if (u == 255) {   // right image edge j=512, both rows
            pa0[512] = eA0; ph0[512] = eH0;
            pa1[512] = eA1; ph1[512] = eH1;
        }
    }

    // odd tail: only strip 64 (nrows == 1) — uses a0,a1,p0,p1 from prologue
    if (ii < nrows) {
        const int i = i0 + ii;
        float4 vloM = comb4(l0, a0m, l1, a1m, l2, p0m, l3, p1m);
        float2 vloE = comb2(l0, a0e, l1, a1e, l2, p0e, l3, p1e);
        float4 vhiM = comb4(h0, a0m, h1, a1m, h2, p0m, h3, p1m);
        float2 vhiE = comb2(h0, a0e, h1, a1e, h2, p0e, h3, p1e);
        if (u == 0) {
            vloE = make_float2(vloM.y, vloM.x);
            vhiE = make_float2(vhiM.y, vhiM.x);
        }
        float oA0 = fmaf(l0, vloE.x, fmaf(l1, vloE.y, fmaf(l2, vloM.x, l3 * vloM.y)));
        float oA1 = fmaf(l0, vloM.x, fmaf(l1, vloM.y, fmaf(l2, vloM.z, l3 * vloM.w)));
        float oH0 = fmaf(l0, vhiE.x, fmaf(l1, vhiE.y, fmaf(l2, vhiM.x, l3 * vhiM.y)));
        float oH1 = fmaf(l0, vhiM.x, fmaf(l1, vhiM.y, fmaf(l2, vhiM.z, l3 * vhiM.w)));
        float* pa = cA + (size_t)i * NOUT;
        float* ph = cH + (size_t)i * NOUT;
        pa[2 * u]     = oA0;
        pa[2 * u + 1] = oA1;
        ph[2 * u]     = oH0;
        ph[2 * u + 1] = oH1;
        if (u == 255) {
            pa[512] = fmaf(l0, vloM.z, fmaf(l1, vloM.w, fmaf(l2, vloM.w, l3 * vloM.z)));
            ph[512] = fmaf(l0, vhiM.z, fmaf(l1, vhiM.w, fmaf(l2, vhiM.w, l3 * vhiM.z)));
        }
    }
}

extern "C" void kernel_launch(void* const* d_in, const int* in_sizes, int n_in,
                              void* d_out, int out_size, void* d_ws, size_t ws_size,
                              hipStream_t stream) {
    (void)in_sizes; (void)n_in; (void)d_ws; (void)ws_size; (void)out_size;
    const float* x = (const float*)d_in[0];
    float* out = (float*)d_out;
    dim3 grid(STRIPS, NIMG);    // 65 x 48 = 3120 blocks
    dim3 block(256);
    dwt2_v4<<<grid, block, 0, stream>>>(x, out);
}

// Round 5
// 306.652 us; speedup vs baseline: 1.0346x; 1.0346x over previous
//
#include <hip/hip_runtime.h>

// 2D DWT (db2, symmetric pad, pywt-compatible) v5: v3 skeleton + ring-of-3
// row-pair prefetch (2-deep MLP) with the v4 compiler failure modes removed.
// x: (16,3,1024,1024) f32 -> cA, cH: (16,3,513,513) f32, concatenated in d_out.
//
//  - v3 proved: TI=8, 256 thr, 3120 blocks, per-row wave-private LDS bounce,
//    dense dword stores, no barriers. Kept verbatim.
//  - Ring A,B,C of xp row-pairs: pair issued at iter k is consumed at k+2.
//    2x in-flight loads/wave vs v3.
//  - Full #pragma unroll over the 8-row strip: ring rotation = register
//    renaming (no movs), prefetch guard is compile-time (nothing to sink).
//  - launch_bounds(256,7): VGPR cap 73 (state 36 + temps fits; v4's cap-64
//    forced VGPR=40 degeneracy). 7 waves/SIMD = 28 waves/CU.

#define N 1024
#define NOUT 513
#define TI 8
#define STRIPS ((NOUT + TI - 1) / TI)   // 65
#define NIMG 48

__device__ __forceinline__ int refl(int p) {
    int r = p - 2;
    r = (r < 0) ? (-1 - r) : r;
    r = (r > N - 1) ? (2 * N - 1 - r) : r;
    return r;
}

__device__ __forceinline__ float4 comb4(float w0, const float4 a, float w1, const float4 b,
                                        float w2, const float4 c, float w3, const float4 d) {
    float4 r;
    r.x = fmaf(w0, a.x, fmaf(w1, b.x, fmaf(w2, c.x, w3 * d.x)));
    r.y = fmaf(w0, a.y, fmaf(w1, b.y, fmaf(w2, c.y, w3 * d.y)));
    r.z = fmaf(w0, a.z, fmaf(w1, b.z, fmaf(w2, c.z, w3 * d.z)));
    r.w = fmaf(w0, a.w, fmaf(w1, b.w, fmaf(w2, c.w, w3 * d.w)));
    return r;
}

__device__ __forceinline__ float2 comb2(float w0, const float2 a, float w1, const float2 b,
                                        float w2, const float2 c, float w3, const float2 d) {
    float2 r;
    r.x = fmaf(w0, a.x, fmaf(w1, b.x, fmaf(w2, c.x, w3 * d.x)));
    r.y = fmaf(w0, a.y, fmaf(w1, b.y, fmaf(w2, c.y, w3 * d.y)));
    return r;
}

__global__ __launch_bounds__(256, 7) void dwt2_v5(const float* __restrict__ x,
                                                  float* __restrict__ out) {
    // reversed filter taps (true convolution)
    const float l0 =  0.48296291314469025f;
    const float l1 =  0.836516303737469f;
    const float l2 =  0.22414386804185735f;
    const float l3 = -0.12940952255092145f;
    const float h0 = -0.12940952255092145f;
    const float h1 = -0.22414386804185735f;
    const float h2 =  0.836516303737469f;
    const float h3 = -0.48296291314469025f;

    __shared__ float sA[4][128];   // wave-private store staging (2 KB)
    __shared__ float sH[4][128];   // 2 KB

    const int strip = blockIdx.x;
    const int img   = blockIdx.y;
    const int i0 = strip * TI;
    const int u    = threadIdx.x;        // 0..255
    const int wave = u >> 6;
    const int lane = u & 63;
    const int c4 = 4 * u;                // owned input cols c4..c4+3
    const int ce = (u == 0) ? 0 : (c4 - 2);

    const float* xim = x + (size_t)img * N * N;
    const size_t plane = (size_t)NOUT * NOUT;
    float* cA = out + (size_t)img * plane;
    float* cH = out + ((size_t)NIMG + img) * plane;

    // ring prologue: A = xp[2i0,2i0+1], B = xp[2i0+2,2i0+3], C = xp[2i0+4,2i0+5]
    const float* q;
    q = xim + (size_t)refl(2 * i0)     * N;
    float4 A0m = *reinterpret_cast<const float4*>(q + c4);
    float2 A0e = *reinterpret_cast<const float2*>(q + ce);
    q = xim + (size_t)refl(2 * i0 + 1) * N;
    float4 A1m = *reinterpret_cast<const float4*>(q + c4);
    float2 A1e = *reinterpret_cast<const float2*>(q + ce);
    q = xim + (size_t)refl(2 * i0 + 2) * N;
    float4 B0m = *reinterpret_cast<const float4*>(q + c4);
    float2 B0e = *reinterpret_cast<const float2*>(q + ce);
    q = xim + (size_t)refl(2 * i0 + 3) * N;
    float4 B1m = *reinterpret_cast<const float4*>(q + c4);
    float2 B1e = *reinterpret_cast<const float2*>(q + ce);
    q = xim + (size_t)refl(2 * i0 + 4) * N;
    float4 C0m = *reinterpret_cast<const float4*>(q + c4);
    float2 C0e = *reinterpret_cast<const float2*>(q + ce);
    q = xim + (size_t)refl(2 * i0 + 5) * N;
    float4 C1m = *reinterpret_cast<const float4*>(q + c4);
    float2 C1e = *reinterpret_cast<const float2*>(q + ce);

    if (i0 + TI <= NOUT) {
        // ---- full strip: nrows == TI == 8, fully unrolled ----
#pragma unroll
        for (int ii = 0; ii < TI; ++ii) {
            const int i = i0 + ii;

            // vertical: output row i from xp rows (A0,A1,B0,B1)
            float4 vloM = comb4(l0, A0m, l1, A1m, l2, B0m, l3, B1m);
            float2 vloE = comb2(l0, A0e, l1, A1e, l2, B0e, l3, B1e);
            float4 vhiM = comb4(h0, A0m, h1, A1m, h2, B0m, h3, B1m);
            float2 vhiE = comb2(h0, A0e, h1, A1e, h2, B0e, h3, B1e);

            if (u == 0) {   // left image edge: j=0 uses xp cols (1,0,0,1)
                vloE = make_float2(vloM.y, vloM.x);
                vhiE = make_float2(vhiM.y, vhiM.x);
            }

            // rotate ring (register renaming under full unroll)
            A0m = B0m; A0e = B0e; A1m = B1m; A1e = B1e;
            B0m = C0m; B0e = C0e; B1m = C1m; B1e = C1e;
            // prefetch into C: consumed 2 iterations from now
            if (ii + 2 < TI) {
                q = xim + (size_t)refl(2 * i + 6) * N;
                C0m = *reinterpret_cast<const float4*>(q + c4);
                C0e = *reinterpret_cast<const float2*>(q + ce);
                q = xim + (size_t)refl(2 * i + 7) * N;
                C1m = *reinterpret_cast<const float4*>(q + c4);
                C1e = *reinterpret_cast<const float2*>(q + ce);
            }

            // horizontal: outputs j=2u, 2u+1 (+ j=512 on u==255)
            float oA0 = fmaf(l0, vloE.x, fmaf(l1, vloE.y, fmaf(l2, vloM.x, l3 * vloM.y)));
            float oA1 = fmaf(l0, vloM.x, fmaf(l1, vloM.y, fmaf(l2, vloM.z, l3 * vloM.w)));
            float oH0 = fmaf(l0, vhiE.x, fmaf(l1, vhiE.y, fmaf(l2, vhiM.x, l3 * vhiM.y)));
            float oH1 = fmaf(l0, vhiM.x, fmaf(l1, vhiM.y, fmaf(l2, vhiM.z, l3 * vhiM.w)));
            float eA  = fmaf(l0, vloM.z, fmaf(l1, vloM.w, fmaf(l2, vloM.w, l3 * vloM.z)));
            float eH  = fmaf(l0, vhiM.z, fmaf(l1, vhiM.w, fmaf(l2, vhiM.w, l3 * vhiM.z)));

            // wave-private LDS bounce -> lane-dense dword stores (v3 verbatim)
            sA[wave][2 * lane]     = oA0;
            sA[wave][2 * lane + 1] = oA1;
            sH[wave][2 * lane]     = oH0;
            sH[wave][2 * lane + 1] = oH1;
            float rA0 = sA[wave][lane];
            float rA1 = sA[wave][64 + lane];
            float rH0 = sH[wave][lane];
            float rH1 = sH[wave][64 + lane];

            const int j0 = (wave << 7) + lane;
            float* pa = cA + (size_t)i * NOUT;
            float* ph = cH + (size_t)i * NOUT;
            pa[j0]      = rA0;
            pa[j0 + 64] = rA1;
            ph[j0]      = rH0;
            ph[j0 + 64] = rH1;

            if (u == 255) {
                pa[512] = eA;
                ph[512] = eH;
            }
        }
    } else {
        // ---- strip 64: single output row i = 512 (uses A,B only) ----
        const int i = i0;
        float4 vloM = comb4(l0, A0m, l1, A1m, l2, B0m, l3, B1m);
        float2 vloE = comb2(l0, A0e, l1, A1e, l2, B0e, l3, B1e);
        float4 vhiM = comb4(h0, A0m, h1, A1m, h2, B0m, h3, B1m);
        float2 vhiE = comb2(h0, A0e, h1, A1e, h2, B0e, h3, B1e);
        if (u == 0) {
            vloE = make_float2(vloM.y, vloM.x);
            vhiE = make_float2(vhiM.y, vhiM.x);
        }
        float oA0 = fmaf(l0, vloE.x, fmaf(l1, vloE.y, fmaf(l2, vloM.x, l3 * vloM.y)));
        float oA1 = fmaf(l0, vloM.x, fmaf(l1, vloM.y, fmaf(l2, vloM.z, l3 * vloM.w)));
        float oH0 = fmaf(l0, vhiE.x, fmaf(l1, vhiE.y, fmaf(l2, vhiM.x, l3 * vhiM.y)));
        float oH1 = fmaf(l0, vhiM.x, fmaf(l1, vhiM.y, fmaf(l2, vhiM.z, l3 * vhiM.w)));
        float* pa = cA + (size_t)i * NOUT;
        float* ph = cH + (size_t)i * NOUT;
        pa[2 * u]     = oA0;
        pa[2 * u + 1] = oA1;
        ph[2 * u]     = oH0;
        ph[2 * u + 1] = oH1;
        if (u == 255) {
            pa[512] = fmaf(l0, vloM.z, fmaf(l1, vloM.w, fmaf(l2, vloM.w, l3 * vloM.z)));
            ph[512] = fmaf(l0, vhiM.z, fmaf(l1, vhiM.w, fmaf(l2, vhiM.w, l3 * vhiM.z)));
        }
        (void)C0m; (void)C0e; (void)C1m; (void)C1e;   // prologue C unused here
    }
}

extern "C" void kernel_launch(void* const* d_in, const int* in_sizes, int n_in,
                              void* d_out, int out_size, void* d_ws, size_t ws_size,
                              hipStream_t stream) {
    (void)in_sizes; (void)n_in; (void)d_ws; (void)ws_size; (void)out_size;
    const float* x = (const float*)d_in[0];
    float* out = (float*)d_out;
    dim3 grid(STRIPS, NIMG);    // 65 x 48 = 3120 blocks
    dim3 block(256);
    dwt2_v5<<<grid, block, 0, stream>>>(x, out);
}

// Round 6
// 298.274 us; speedup vs baseline: 1.0637x; 1.0281x over previous
//
#include <hip/hip_runtime.h>

// 2D DWT (db2, symmetric pad, pywt-compatible) v6: v5 + TI 8->4 (drain-tail fix).
// x: (16,3,1024,1024) f32 -> cA, cH: (16,3,513,513) f32, concatenated in d_out.
//
// v5 (306.7us) = TI=8, 256 thr, depth-2 ring-of-3 prefetch, full unroll,
// wave-private LDS bounce, dense dword stores, LB(256,7).
// v6 theory: remaining gap is launch-granularity drain (1792 resident blocks,
// 1.74 passes, T_block ~33us -> ~10us tail loss). TI=4 doubles the grid to
// 6192 blocks (3.46 passes, T_block ~17us), halving the drain tail. The +11%
// row-overlap re-reads are L2/L3 hits (HBM FETCH barely moves).

#define N 1024
#define NOUT 513
#define TI 4
#define STRIPS ((NOUT + TI - 1) / TI)   // 129
#define NIMG 48

__device__ __forceinline__ int refl(int p) {
    int r = p - 2;
    r = (r < 0) ? (-1 - r) : r;
    r = (r > N - 1) ? (2 * N - 1 - r) : r;
    return r;
}

__device__ __forceinline__ float4 comb4(float w0, const float4 a, float w1, const float4 b,
                                        float w2, const float4 c, float w3, const float4 d) {
    float4 r;
    r.x = fmaf(w0, a.x, fmaf(w1, b.x, fmaf(w2, c.x, w3 * d.x)));
    r.y = fmaf(w0, a.y, fmaf(w1, b.y, fmaf(w2, c.y, w3 * d.y)));
    r.z = fmaf(w0, a.z, fmaf(w1, b.z, fmaf(w2, c.z, w3 * d.z)));
    r.w = fmaf(w0, a.w, fmaf(w1, b.w, fmaf(w2, c.w, w3 * d.w)));
    return r;
}

__device__ __forceinline__ float2 comb2(float w0, const float2 a, float w1, const float2 b,
                                        float w2, const float2 c, float w3, const float2 d) {
    float2 r;
    r.x = fmaf(w0, a.x, fmaf(w1, b.x, fmaf(w2, c.x, w3 * d.x)));
    r.y = fmaf(w0, a.y, fmaf(w1, b.y, fmaf(w2, c.y, w3 * d.y)));
    return r;
}

__global__ __launch_bounds__(256, 7) void dwt2_v6(const float* __restrict__ x,
                                                  float* __restrict__ out) {
    // reversed filter taps (true convolution)
    const float l0 =  0.48296291314469025f;
    const float l1 =  0.836516303737469f;
    const float l2 =  0.22414386804185735f;
    const float l3 = -0.12940952255092145f;
    const float h0 = -0.12940952255092145f;
    const float h1 = -0.22414386804185735f;
    const float h2 =  0.836516303737469f;
    const float h3 = -0.48296291314469025f;

    __shared__ float sA[4][128];   // wave-private store staging (2 KB)
    __shared__ float sH[4][128];   // 2 KB

    const int strip = blockIdx.x;
    const int img   = blockIdx.y;
    const int i0 = strip * TI;
    const int u    = threadIdx.x;        // 0..255
    const int wave = u >> 6;
    const int lane = u & 63;
    const int c4 = 4 * u;                // owned input cols c4..c4+3
    const int ce = (u == 0) ? 0 : (c4 - 2);

    const float* xim = x + (size_t)img * N * N;
    const size_t plane = (size_t)NOUT * NOUT;
    float* cA = out + (size_t)img * plane;
    float* cH = out + ((size_t)NIMG + img) * plane;

    // ring prologue: A = xp[2i0,2i0+1], B = xp[2i0+2,2i0+3], C = xp[2i0+4,2i0+5]
    const float* q;
    q = xim + (size_t)refl(2 * i0)     * N;
    float4 A0m = *reinterpret_cast<const float4*>(q + c4);
    float2 A0e = *reinterpret_cast<const float2*>(q + ce);
    q = xim + (size_t)refl(2 * i0 + 1) * N;
    float4 A1m = *reinterpret_cast<const float4*>(q + c4);
    float2 A1e = *reinterpret_cast<const float2*>(q + ce);
    q = xim + (size_t)refl(2 * i0 + 2) * N;
    float4 B0m = *reinterpret_cast<const float4*>(q + c4);
    float2 B0e = *reinterpret_cast<const float2*>(q + ce);
    q = xim + (size_t)refl(2 * i0 + 3) * N;
    float4 B1m = *reinterpret_cast<const float4*>(q + c4);
    float2 B1e = *reinterpret_cast<const float2*>(q + ce);
    q = xim + (size_t)refl(2 * i0 + 4) * N;
    float4 C0m = *reinterpret_cast<const float4*>(q + c4);
    float2 C0e = *reinterpret_cast<const float2*>(q + ce);
    q = xim + (size_t)refl(2 * i0 + 5) * N;
    float4 C1m = *reinterpret_cast<const float4*>(q + c4);
    float2 C1e = *reinterpret_cast<const float2*>(q + ce);

    if (i0 + TI <= NOUT) {
        // ---- full strip: nrows == TI == 4, fully unrolled ----
#pragma unroll
        for (int ii = 0; ii < TI; ++ii) {
            const int i = i0 + ii;

            // vertical: output row i from xp rows (A0,A1,B0,B1)
            float4 vloM = comb4(l0, A0m, l1, A1m, l2, B0m, l3, B1m);
            float2 vloE = comb2(l0, A0e, l1, A1e, l2, B0e, l3, B1e);
            float4 vhiM = comb4(h0, A0m, h1, A1m, h2, B0m, h3, B1m);
            float2 vhiE = comb2(h0, A0e, h1, A1e, h2, B0e, h3, B1e);

            if (u == 0) {   // left image edge: j=0 uses xp cols (1,0,0,1)
                vloE = make_float2(vloM.y, vloM.x);
                vhiE = make_float2(vhiM.y, vhiM.x);
            }

            // rotate ring (register renaming under full unroll)
            A0m = B0m; A0e = B0e; A1m = B1m; A1e = B1e;
            B0m = C0m; B0e = C0e; B1m = C1m; B1e = C1e;
            // prefetch into C: consumed 2 iterations from now
            if (ii + 2 < TI) {
                q = xim + (size_t)refl(2 * i + 6) * N;
                C0m = *reinterpret_cast<const float4*>(q + c4);
                C0e = *reinterpret_cast<const float2*>(q + ce);
                q = xim + (size_t)refl(2 * i + 7) * N;
                C1m = *reinterpret_cast<const float4*>(q + c4);
                C1e = *reinterpret_cast<const float2*>(q + ce);
            }

            // horizontal: outputs j=2u, 2u+1 (+ j=512 on u==255)
            float oA0 = fmaf(l0, vloE.x, fmaf(l1, vloE.y, fmaf(l2, vloM.x, l3 * vloM.y)));
            float oA1 = fmaf(l0, vloM.x, fmaf(l1, vloM.y, fmaf(l2, vloM.z, l3 * vloM.w)));
            float oH0 = fmaf(l0, vhiE.x, fmaf(l1, vhiE.y, fmaf(l2, vhiM.x, l3 * vhiM.y)));
            float oH1 = fmaf(l0, vhiM.x, fmaf(l1, vhiM.y, fmaf(l2, vhiM.z, l3 * vhiM.w)));
            float eA  = fmaf(l0, vloM.z, fmaf(l1, vloM.w, fmaf(l2, vloM.w, l3 * vloM.z)));
            float eH  = fmaf(l0, vhiM.z, fmaf(l1, vhiM.w, fmaf(l2, vhiM.w, l3 * vhiM.z)));

            // wave-private LDS bounce -> lane-dense dword stores
            sA[wave][2 * lane]     = oA0;
            sA[wave][2 * lane + 1] = oA1;
            sH[wave][2 * lane]     = oH0;
            sH[wave][2 * lane + 1] = oH1;
            float rA0 = sA[wave][lane];
            float rA1 = sA[wave][64 + lane];
            float rH0 = sH[wave][lane];
            float rH1 = sH[wave][64 + lane];

            const int j0 = (wave << 7) + lane;
            float* pa = cA + (size_t)i * NOUT;
            float* ph = cH + (size_t)i * NOUT;
            pa[j0]      = rA0;
            pa[j0 + 64] = rA1;
            ph[j0]      = rH0;
            ph[j0 + 64] = rH1;

            if (u == 255) {
                pa[512] = eA;
                ph[512] = eH;
            }
        }
    } else {
        // ---- strip 128: single output row i = 512 (uses A,B only) ----
        const int i = i0;
        float4 vloM = comb4(l0, A0m, l1, A1m, l2, B0m, l3, B1m);
        float2 vloE = comb2(l0, A0e, l1, A1e, l2, B0e, l3, B1e);
        float4 vhiM = comb4(h0, A0m, h1, A1m, h2, B0m, h3, B1m);
        float2 vhiE = comb2(h0, A0e, h1, A1e, h2, B0e, h3, B1e);
        if (u == 0) {
            vloE = make_float2(vloM.y, vloM.x);
            vhiE = make_float2(vhiM.y, vhiM.x);
        }
        float oA0 = fmaf(l0, vloE.x, fmaf(l1, vloE.y, fmaf(l2, vloM.x, l3 * vloM.y)));
        float oA1 = fmaf(l0, vloM.x, fmaf(l1, vloM.y, fmaf(l2, vloM.z, l3 * vloM.w)));
        float oH0 = fmaf(l0, vhiE.x, fmaf(l1, vhiE.y, fmaf(l2, vhiM.x, l3 * vhiM.y)));
        float oH1 = fmaf(l0, vhiM.x, fmaf(l1, vhiM.y, fmaf(l2, vhiM.z, l3 * vhiM.w)));
        float* pa = cA + (size_t)i * NOUT;
        float* ph = cH + (size_t)i * NOUT;
        pa[2 * u]     = oA0;
        pa[2 * u + 1] = oA1;
        ph[2 * u]     = oH0;
        ph[2 * u + 1] = oH1;
        if (u == 255) {
            pa[512] = fmaf(l0, vloM.z, fmaf(l1, vloM.w, fmaf(l2, vloM.w, l3 * vloM.z)));
            ph[512] = fmaf(l0, vhiM.z, fmaf(l1, vhiM.w, fmaf(l2, vhiM.w, l3 * vhiM.z)));
        }
        (void)C0m; (void)C0e; (void)C1m; (void)C1e;   // prologue C unused here
    }
}

extern "C" void kernel_launch(void* const* d_in, const int* in_sizes, int n_in,
                              void* d_out, int out_size, void* d_ws, size_t ws_size,
                              hipStream_t stream) {
    (void)in_sizes; (void)n_in; (void)d_ws; (void)ws_size; (void)out_size;
    const float* x = (const float*)d_in[0];
    float* out = (float*)d_out;
    dim3 grid(STRIPS, NIMG);    // 129 x 48 = 6192 blocks
    dim3 block(256);
    dwt2_v6<<<grid, block, 0, stream>>>(x, out);
}